// Round 1
// baseline (256.636 us; speedup 1.0000x reference)
//
#include <hip/hip_runtime.h>
#include <stdint.h>

typedef __bf16 bf16;
typedef __bf16 bf16x4_t __attribute__((ext_vector_type(4)));
typedef __bf16 bf16x8_t __attribute__((ext_vector_type(8)));
typedef float f32x4 __attribute__((ext_vector_type(4)));

static constexpr int NB = 2, SS = 2048, DD = 1024, NH = 16, HD = 64;

__device__ __forceinline__ void gl_lds16(const void* g, void* l) {
    __builtin_amdgcn_global_load_lds((__attribute__((address_space(1))) void*)g,
                                     (__attribute__((address_space(3))) void*)l, 16, 0, 0);
}

// ---------------- fp32 -> bf16 cast, float4 vectorized ----------------
__global__ __launch_bounds__(256) void cast_kernel(const float* __restrict__ src,
                                                   bf16* __restrict__ dst, int n4) {
    int i = blockIdx.x * 256 + threadIdx.x;
    if (i < n4) {
        float4 v = reinterpret_cast<const float4*>(src)[i];
        bf16x4_t o;
        o.x = (bf16)v.x; o.y = (bf16)v.y; o.z = (bf16)v.z; o.w = (bf16)v.w;
        reinterpret_cast<bf16x4_t*>(dst)[i] = o;
    }
}

// ---------------- shared 128x128 NT-GEMM mainloop (m97 structure) ----------------
// C[128,128] = A[128,K] * B[128,K]^T, bf16 in, fp32 acc. BK=32.
// LDS staged via global_load_lds width=16 with XOR chunk swizzle:
//   row of 32 elems = 4 chunks of 16B; LDS chunk c' holds global chunk c'^((row>>1)&3)
//   -> frag ds_read_b128 spreads over 8 bank-groups (2-way = free, m136).
__device__ __forceinline__ void gemm128_mainloop(const bf16* __restrict__ Ablk,
                                                 const bf16* __restrict__ Bblk,
                                                 int K, f32x4 acc[4][4]) {
    __shared__ __align__(16) bf16 As[128 * 32];
    __shared__ __align__(16) bf16 Bs[128 * 32];
    const int tid = threadIdx.x;
    const int wave = tid >> 6, lane = tid & 63;
    const int quad = lane >> 4, l15 = lane & 15;
    const int wm = wave >> 1, wn = wave & 1;

#pragma unroll
    for (int mi = 0; mi < 4; mi++)
#pragma unroll
        for (int ni = 0; ni < 4; ni++) {
            acc[mi][ni][0] = 0.f; acc[mi][ni][1] = 0.f;
            acc[mi][ni][2] = 0.f; acc[mi][ni][3] = 0.f;
        }

    // staging chunk indices (chunk = 16B = 8 bf16), 512 chunks/tile, 2 issues/thread
    const int n0c = tid;        // issue 0
    const int r0 = n0c >> 2, c0 = (n0c & 3) ^ ((r0 >> 1) & 3);
    const int n1c = 256 + tid;  // issue 1
    const int r1 = n1c >> 2, c1 = (n1c & 3) ^ ((r1 >> 1) & 3);

    for (int kk = 0; kk < K; kk += 32) {
        __syncthreads();
        gl_lds16(Ablk + (size_t)r0 * K + kk + c0 * 8, &As[(wave * 64) * 8]);
        gl_lds16(Ablk + (size_t)r1 * K + kk + c1 * 8, &As[(256 + wave * 64) * 8]);
        gl_lds16(Bblk + (size_t)r0 * K + kk + c0 * 8, &Bs[(wave * 64) * 8]);
        gl_lds16(Bblk + (size_t)r1 * K + kk + c1 * 8, &Bs[(256 + wave * 64) * 8]);
        __syncthreads();

        bf16x8_t a[4], b[4];
#pragma unroll
        for (int mi = 0; mi < 4; mi++) {
            int R = wm * 64 + mi * 16 + l15;
            a[mi] = *(const bf16x8_t*)&As[R * 32 + ((quad ^ ((R >> 1) & 3)) << 3)];
        }
#pragma unroll
        for (int ni = 0; ni < 4; ni++) {
            int R = wn * 64 + ni * 16 + l15;
            b[ni] = *(const bf16x8_t*)&Bs[R * 32 + ((quad ^ ((R >> 1) & 3)) << 3)];
        }
#pragma unroll
        for (int mi = 0; mi < 4; mi++)
#pragma unroll
            for (int ni = 0; ni < 4; ni++)
                acc[mi][ni] = __builtin_amdgcn_mfma_f32_16x16x32_bf16(a[mi], b[ni], acc[mi][ni], 0, 0, 0);
    }
}

// ---------------- QKV projection: C[4096,3072] scattered to Q/K/V [B,H,S,HD] bf16 ----------------
__global__ __launch_bounds__(256) void gemm_qkv(const bf16* __restrict__ A, const bf16* __restrict__ Wqkv,
                                                const float* __restrict__ bq, const float* __restrict__ bk,
                                                const float* __restrict__ bv,
                                                bf16* __restrict__ Qb, bf16* __restrict__ Kb, bf16* __restrict__ Vb) {
    const int m0 = blockIdx.x * 128;
    const int n0 = blockIdx.y * 128;
    f32x4 acc[4][4];
    gemm128_mainloop(A + (size_t)m0 * DD, Wqkv + (size_t)n0 * DD, DD, acc);

    const int tid = threadIdx.x, wave = tid >> 6, lane = tid & 63;
    const int quad = lane >> 4, l15 = lane & 15;
    const int wm = wave >> 1, wn = wave & 1;

    const int which = n0 >> 10;  // 0:Q 1:K 2:V (128-col block never straddles)
    const float* bias = (which == 0) ? bq : (which == 1) ? bk : bv;
    bf16* dst = (which == 0) ? Qb : (which == 1) ? Kb : Vb;

    const int cbase = (n0 & 1023) + wn * 64;  // multiple of 64
    const int head = cbase >> 6;
    const int bb = m0 >> 11;
    const int s0 = (m0 & 2047) + wm * 64;
    bf16* dbase = dst + ((size_t)(bb * NH + head)) * SS * HD;

#pragma unroll
    for (int ni = 0; ni < 4; ni++) {
        float bsv = bias[cbase + ni * 16 + l15];
        int hd = ni * 16 + l15;
#pragma unroll
        for (int mi = 0; mi < 4; mi++) {
#pragma unroll
            for (int r = 0; r < 4; r++) {
                int s = s0 + mi * 16 + quad * 4 + r;
                dbase[(size_t)s * HD + hd] = (bf16)(acc[mi][ni][r] + bsv);
            }
        }
    }
}

// ---------------- output projection: fp32 out ----------------
__global__ __launch_bounds__(256) void gemm_out(const bf16* __restrict__ A, const bf16* __restrict__ Wo,
                                                const float* __restrict__ bo, float* __restrict__ out) {
    const int m0 = blockIdx.x * 128, n0 = blockIdx.y * 128;
    f32x4 acc[4][4];
    gemm128_mainloop(A + (size_t)m0 * DD, Wo + (size_t)n0 * DD, DD, acc);

    const int tid = threadIdx.x, wave = tid >> 6, lane = tid & 63;
    const int quad = lane >> 4, l15 = lane & 15;
    const int wm = wave >> 1, wn = wave & 1;
    float* obase = out + (size_t)(m0 + wm * 64) * DD + n0 + wn * 64;
#pragma unroll
    for (int ni = 0; ni < 4; ni++) {
        float bias = bo[n0 + wn * 64 + ni * 16 + l15];
#pragma unroll
        for (int mi = 0; mi < 4; mi++)
#pragma unroll
            for (int r = 0; r < 4; r++)
                obase[(size_t)(mi * 16 + quad * 4 + r) * DD + ni * 16 + l15] = acc[mi][ni][r] + bias;
    }
}

// ---------------- causal flash attention: Q-tile 128, K/V-tile 128, HD=64 ----------------
// Q,K,V: [B*H, S, 64] bf16. O written as [B, S, H*64] bf16 (ready for out-proj GEMM).
// Per block: 4 waves; wave w owns Q rows [w*32, w*32+32). K staged via swizzled
// global_load_lds; V staged transposed ([hd][key], pad 136) by VALU; P round-trips
// LDS ([128][136] pad) for the C->A layout transform (m120 pattern).
__global__ __launch_bounds__(256) void attn_kernel(const bf16* __restrict__ Qb, const bf16* __restrict__ Kb,
                                                   const bf16* __restrict__ Vb, bf16* __restrict__ Ob) {
    __shared__ __align__(16) bf16 Kt[128 * 64];
    __shared__ __align__(16) bf16 Vt[64 * 136];
    __shared__ __align__(16) bf16 Pt[128 * 136];

    const int tid = threadIdx.x, wave = tid >> 6, lane = tid & 63;
    const int quad = lane >> 4, l15 = lane & 15;
    const int qtile = blockIdx.x, bh = blockIdx.y;
    const size_t hoff = (size_t)bh * SS * HD;
    const bf16* Qg = Qb + hoff + (size_t)qtile * 128 * HD;

    // Q fragments straight from global (16B/lane, one-time)
    bf16x8_t qf[2][2];
#pragma unroll
    for (int mt = 0; mt < 2; mt++)
#pragma unroll
        for (int ks = 0; ks < 2; ks++)
            qf[mt][ks] = *(const bf16x8_t*)(Qg + (wave * 32 + mt * 16 + l15) * HD + ks * 32 + quad * 8);

    f32x4 o[2][4];
#pragma unroll
    for (int mt = 0; mt < 2; mt++)
#pragma unroll
        for (int nO = 0; nO < 4; nO++) {
            o[mt][nO][0] = 0.f; o[mt][nO][1] = 0.f; o[mt][nO][2] = 0.f; o[mt][nO][3] = 0.f;
        }
    float mrow[2][4], lrow[2][4];
#pragma unroll
    for (int mt = 0; mt < 2; mt++)
#pragma unroll
        for (int r = 0; r < 4; r++) { mrow[mt][r] = -__builtin_inff(); lrow[mt][r] = 0.f; }

    const float scale = 0.125f;  // 1/sqrt(64)

    for (int j = 0; j <= qtile; j++) {
        __syncthreads();
        // stage K tile [128][64] with XOR swizzle (8 chunks/row; c' holds gc = c'^(row&7))
        const bf16* Kg = Kb + hoff + (size_t)j * 128 * HD;
#pragma unroll
        for (int i = 0; i < 4; i++) {
            int n = i * 256 + tid;
            int row = n >> 3;
            int gc = (n & 7) ^ (row & 7);
            gl_lds16(Kg + row * HD + gc * 8, &Kt[(i * 256 + wave * 64) * 8]);
        }
        // stage V transposed: Vt[hd][key], pad 136
        const bf16* Vg = Vb + hoff + (size_t)j * 128 * HD;
#pragma unroll
        for (int p = 0; p < 4; p++) {
            int task = p * 256 + tid;
            int key = task & 127;
            int hd0 = (task >> 7) * 8;
            bf16x8_t v = *(const bf16x8_t*)(Vg + key * HD + hd0);
#pragma unroll
            for (int jj = 0; jj < 8; jj++) Vt[(hd0 + jj) * 136 + key] = v[jj];
        }
        __syncthreads();

        // S = Q K^T  (per wave: 2 m-tiles x 8 n-tiles)
        f32x4 sfr[2][8];
#pragma unroll
        for (int mt = 0; mt < 2; mt++)
#pragma unroll
            for (int nt = 0; nt < 8; nt++) {
                sfr[mt][nt][0] = 0.f; sfr[mt][nt][1] = 0.f; sfr[mt][nt][2] = 0.f; sfr[mt][nt][3] = 0.f;
            }
#pragma unroll
        for (int ks = 0; ks < 2; ks++) {
#pragma unroll
            for (int nt = 0; nt < 8; nt++) {
                int R = nt * 16 + l15;
                bf16x8_t kf = *(const bf16x8_t*)&Kt[R * HD + ((((ks << 2) | quad) ^ (R & 7)) << 3)];
#pragma unroll
                for (int mt = 0; mt < 2; mt++)
                    sfr[mt][nt] = __builtin_amdgcn_mfma_f32_16x16x32_bf16(qf[mt][ks], kf, sfr[mt][nt], 0, 0, 0);
            }
        }

        // online softmax per row (C layout: col=l15, row=quad*4+r)
        const bool diag = (j == qtile);
#pragma unroll
        for (int mt = 0; mt < 2; mt++) {
#pragma unroll
            for (int r = 0; r < 4; r++) {
                const int rowl = wave * 32 + mt * 16 + quad * 4 + r;
                float vals[8];
                float mx = -__builtin_inff();
#pragma unroll
                for (int nt = 0; nt < 8; nt++) {
                    float v = sfr[mt][nt][r] * scale;
                    if (diag && (nt * 16 + l15 > rowl)) v = -__builtin_inff();
                    vals[nt] = v;
                    mx = fmaxf(mx, v);
                }
#pragma unroll
                for (int d = 1; d < 16; d <<= 1) mx = fmaxf(mx, __shfl_xor(mx, d));
                float mold = mrow[mt][r];
                float mnew = fmaxf(mold, mx);
                float alpha = __expf(mold - mnew);
                mrow[mt][r] = mnew;
                float sum = 0.f;
#pragma unroll
                for (int nt = 0; nt < 8; nt++) {
                    float p = __expf(vals[nt] - mnew);
                    sum += p;
                    Pt[rowl * 136 + nt * 16 + l15] = (bf16)p;
                }
#pragma unroll
                for (int d = 1; d < 16; d <<= 1) sum += __shfl_xor(sum, d);
                lrow[mt][r] = lrow[mt][r] * alpha + sum;
#pragma unroll
                for (int nO = 0; nO < 4; nO++) o[mt][nO][r] *= alpha;
            }
        }

        // O += P V   (P A-frags from own LDS strip; V^T B-frags from Vt)
#pragma unroll
        for (int ks = 0; ks < 4; ks++) {
            bf16x8_t pf[2];
#pragma unroll
            for (int mt = 0; mt < 2; mt++)
                pf[mt] = *(const bf16x8_t*)&Pt[(wave * 32 + mt * 16 + l15) * 136 + ks * 32 + quad * 8];
#pragma unroll
            for (int nO = 0; nO < 4; nO++) {
                bf16x8_t vf = *(const bf16x8_t*)&Vt[(nO * 16 + l15) * 136 + ks * 32 + quad * 8];
#pragma unroll
                for (int mt = 0; mt < 2; mt++)
                    o[mt][nO] = __builtin_amdgcn_mfma_f32_16x16x32_bf16(pf[mt], vf, o[mt][nO], 0, 0, 0);
            }
        }
    }

    // epilogue: O/l -> Ob [B, S, H*64] bf16
    const int bb = bh >> 4, hh = bh & 15;
#pragma unroll
    for (int mt = 0; mt < 2; mt++) {
#pragma unroll
        for (int r = 0; r < 4; r++) {
            int srow = qtile * 128 + wave * 32 + mt * 16 + quad * 4 + r;
            float inv = 1.f / lrow[mt][r];
#pragma unroll
            for (int nO = 0; nO < 4; nO++)
                Ob[((size_t)(bb * SS + srow)) * DD + hh * HD + nO * 16 + l15] = (bf16)(o[mt][nO][r] * inv);
        }
    }
}

// ---------------- host launcher ----------------
extern "C" void kernel_launch(void* const* d_in, const int* in_sizes, int n_in,
                              void* d_out, int out_size, void* d_ws, size_t ws_size,
                              hipStream_t stream) {
    (void)in_sizes; (void)n_in; (void)out_size; (void)ws_size;
    const float* h  = (const float*)d_in[0];
    const float* Wq = (const float*)d_in[1];
    const float* bq = (const float*)d_in[2];
    const float* Wk = (const float*)d_in[3];
    const float* bk = (const float*)d_in[4];
    const float* Wv = (const float*)d_in[5];
    const float* bv = (const float*)d_in[6];
    const float* Wo = (const float*)d_in[7];
    const float* bo = (const float*)d_in[8];
    float* out = (float*)d_out;

    // workspace layout (bytes): total 50,331,648
    char* ws = (char*)d_ws;
    bf16* hbf  = (bf16*)(ws);                                  //  8,388,608  h bf16 [4096,1024]
    bf16* wqkv = (bf16*)(ws + 8388608);                        //  6,291,456  Wq|Wk|Wv bf16 [3072,1024]
    bf16* wo   = (bf16*)(ws + 8388608 + 6291456);              //  2,097,152  Wo bf16
    bf16* Qb   = (bf16*)(ws + 16777216);                       //  8,388,608  [B,H,S,64]
    bf16* Kb   = (bf16*)(ws + 16777216 + 8388608);             //  8,388,608
    bf16* Vb   = (bf16*)(ws + 16777216 + 2 * 8388608);         //  8,388,608
    bf16* Ob   = (bf16*)(ws + 16777216 + 3 * 8388608);         //  8,388,608  [B,S,H*64]

    cast_kernel<<<4096, 256, 0, stream>>>(h,  hbf, 1048576);
    cast_kernel<<<1024, 256, 0, stream>>>(Wq, wqkv,           262144);
    cast_kernel<<<1024, 256, 0, stream>>>(Wk, wqkv + 1048576, 262144);
    cast_kernel<<<1024, 256, 0, stream>>>(Wv, wqkv + 2097152, 262144);
    cast_kernel<<<1024, 256, 0, stream>>>(Wo, wo, 262144);

    gemm_qkv<<<dim3(32, 24), 256, 0, stream>>>(hbf, wqkv, bq, bk, bv, Qb, Kb, Vb);
    attn_kernel<<<dim3(16, 32), 256, 0, stream>>>(Qb, Kb, Vb, Ob);
    gemm_out<<<dim3(32, 8), 256, 0, stream>>>(Ob, wo, bo, out);
}

// Round 3
// 205.687 us; speedup vs baseline: 1.2477x; 1.2477x over previous
//
#include <hip/hip_runtime.h>
#include <stdint.h>

typedef __bf16 bf16;
typedef __bf16 bf16x4_t __attribute__((ext_vector_type(4)));
typedef __bf16 bf16x8_t __attribute__((ext_vector_type(8)));
typedef float f32x4 __attribute__((ext_vector_type(4)));

static constexpr int NB = 2, SS = 2048, DD = 1024, NH = 16, HD = 64;

__device__ __forceinline__ void gl_lds16(const void* g, void* l) {
    __builtin_amdgcn_global_load_lds((__attribute__((address_space(1))) void*)g,
                                     (__attribute__((address_space(3))) void*)l, 16, 0, 0);
}

// ---------------- fused fp32 -> bf16 cast of h + Wq + Wk + Wv + Wo ----------------
// dst layout: [hbf 1048576 f4][Wq 262144][Wk 262144][Wv 262144][Wo 262144] contiguous.
__global__ __launch_bounds__(256) void cast_all(const float* __restrict__ h,
                                                const float* __restrict__ Wq,
                                                const float* __restrict__ Wk,
                                                const float* __restrict__ Wv,
                                                const float* __restrict__ Wo,
                                                bf16* __restrict__ dst) {
    int i = blockIdx.x * 256 + threadIdx.x;  // float4 index, grid covers exactly 2097152
    const float* src;
    int off;
    if (i < 1048576) { src = h; off = i; }
    else {
        int r = i - 1048576;
        int w = r >> 18;
        off = r & 262143;
        src = (w == 0) ? Wq : (w == 1) ? Wk : (w == 2) ? Wv : Wo;
    }
    float4 v = reinterpret_cast<const float4*>(src)[off];
    bf16x4_t o;
    o.x = (bf16)v.x; o.y = (bf16)v.y; o.z = (bf16)v.z; o.w = (bf16)v.w;
    reinterpret_cast<bf16x4_t*>(dst)[i] = o;
}

// ---------------- shared 128x128 NT-GEMM mainloop (m97 structure) ----------------
__device__ __forceinline__ void gemm128_mainloop(const bf16* __restrict__ Ablk,
                                                 const bf16* __restrict__ Bblk,
                                                 int K, f32x4 acc[4][4]) {
    __shared__ __align__(16) bf16 As[128 * 32];
    __shared__ __align__(16) bf16 Bs[128 * 32];
    const int tid = threadIdx.x;
    const int wave = tid >> 6, lane = tid & 63;
    const int quad = lane >> 4, l15 = lane & 15;
    const int wm = wave >> 1, wn = wave & 1;

#pragma unroll
    for (int mi = 0; mi < 4; mi++)
#pragma unroll
        for (int ni = 0; ni < 4; ni++) {
            acc[mi][ni][0] = 0.f; acc[mi][ni][1] = 0.f;
            acc[mi][ni][2] = 0.f; acc[mi][ni][3] = 0.f;
        }

    const int n0c = tid;
    const int r0 = n0c >> 2, c0 = (n0c & 3) ^ ((r0 >> 1) & 3);
    const int n1c = 256 + tid;
    const int r1 = n1c >> 2, c1 = (n1c & 3) ^ ((r1 >> 1) & 3);

    for (int kk = 0; kk < K; kk += 32) {
        __syncthreads();
        gl_lds16(Ablk + (size_t)r0 * K + kk + c0 * 8, &As[(wave * 64) * 8]);
        gl_lds16(Ablk + (size_t)r1 * K + kk + c1 * 8, &As[(256 + wave * 64) * 8]);
        gl_lds16(Bblk + (size_t)r0 * K + kk + c0 * 8, &Bs[(wave * 64) * 8]);
        gl_lds16(Bblk + (size_t)r1 * K + kk + c1 * 8, &Bs[(256 + wave * 64) * 8]);
        __syncthreads();

        bf16x8_t a[4], b[4];
#pragma unroll
        for (int mi = 0; mi < 4; mi++) {
            int R = wm * 64 + mi * 16 + l15;
            a[mi] = *(const bf16x8_t*)&As[R * 32 + ((quad ^ ((R >> 1) & 3)) << 3)];
        }
#pragma unroll
        for (int ni = 0; ni < 4; ni++) {
            int R = wn * 64 + ni * 16 + l15;
            b[ni] = *(const bf16x8_t*)&Bs[R * 32 + ((quad ^ ((R >> 1) & 3)) << 3)];
        }
#pragma unroll
        for (int mi = 0; mi < 4; mi++)
#pragma unroll
            for (int ni = 0; ni < 4; ni++)
                acc[mi][ni] = __builtin_amdgcn_mfma_f32_16x16x32_bf16(a[mi], b[ni], acc[mi][ni], 0, 0, 0);
    }
}

// ---------------- QKV projection ----------------
// Q is pre-scaled by 0.125 * log2(e) so attention can use exp2 directly.
__global__ __launch_bounds__(256) void gemm_qkv(const bf16* __restrict__ A, const bf16* __restrict__ Wqkv,
                                                const float* __restrict__ bq, const float* __restrict__ bk,
                                                const float* __restrict__ bv,
                                                bf16* __restrict__ Qb, bf16* __restrict__ Kb, bf16* __restrict__ Vb) {
    const int m0 = blockIdx.x * 128;
    const int n0 = blockIdx.y * 128;
    f32x4 acc[4][4];
    gemm128_mainloop(A + (size_t)m0 * DD, Wqkv + (size_t)n0 * DD, DD, acc);

    const int tid = threadIdx.x, wave = tid >> 6, lane = tid & 63;
    const int quad = lane >> 4, l15 = lane & 15;
    const int wm = wave >> 1, wn = wave & 1;

    const int which = n0 >> 10;
    const float* bias = (which == 0) ? bq : (which == 1) ? bk : bv;
    bf16* dst = (which == 0) ? Qb : (which == 1) ? Kb : Vb;
    const float sc = (which == 0) ? 0.18033688f : 1.0f;  // 0.125 * log2(e)

    const int cbase = (n0 & 1023) + wn * 64;
    const int head = cbase >> 6;
    const int bb = m0 >> 11;
    const int s0 = (m0 & 2047) + wm * 64;
    bf16* dbase = dst + ((size_t)(bb * NH + head)) * SS * HD;

#pragma unroll
    for (int ni = 0; ni < 4; ni++) {
        float bsv = bias[cbase + ni * 16 + l15];
        int hd = ni * 16 + l15;
#pragma unroll
        for (int mi = 0; mi < 4; mi++) {
#pragma unroll
            for (int r = 0; r < 4; r++) {
                int s = s0 + mi * 16 + quad * 4 + r;
                dbase[(size_t)s * HD + hd] = (bf16)((acc[mi][ni][r] + bsv) * sc);
            }
        }
    }
}

// ---------------- output projection: fp32 out ----------------
__global__ __launch_bounds__(256) void gemm_out(const bf16* __restrict__ A, const bf16* __restrict__ Wo,
                                                const float* __restrict__ bo, float* __restrict__ out) {
    const int m0 = blockIdx.x * 128, n0 = blockIdx.y * 128;
    f32x4 acc[4][4];
    gemm128_mainloop(A + (size_t)m0 * DD, Wo + (size_t)n0 * DD, DD, acc);

    const int tid = threadIdx.x, wave = tid >> 6, lane = tid & 63;
    const int quad = lane >> 4, l15 = lane & 15;
    const int wm = wave >> 1, wn = wave & 1;
    float* obase = out + (size_t)(m0 + wm * 64) * DD + n0 + wn * 64;
#pragma unroll
    for (int ni = 0; ni < 4; ni++) {
        float bias = bo[n0 + wn * 64 + ni * 16 + l15];
#pragma unroll
        for (int mi = 0; mi < 4; mi++)
#pragma unroll
            for (int r = 0; r < 4; r++)
                obase[(size_t)(mi * 16 + quad * 4 + r) * DD + ni * 16 + l15] = acc[mi][ni][r] + bias;
    }
}

// ---------------- causal flash attention, S^T formulation ----------------
// Q pre-scaled by 0.125*log2e. Per block: Q-tile 128 rows, 4 waves x 32 rows.
// S^T = mfma(A=K, B=Q): lane holds S^T[key=16kt+4q+r][qrow=16qt+l15] ->
// softmax reduce = 16 in-lane fmax + 2 quad-shuffles per qt; P written as b64
// (4 consecutive keys) to a per-wave swizzled LDS strip, read back as b128
// A-frags for O = P*V. KV processed in 64-key halves (small P strip, lower regs).
// Block mapping pairs qtile (15-i) at x with qtile (i) at x+256 for CU balance.
__global__ __launch_bounds__(256, 3) void attn_kernel(const bf16* __restrict__ Qb, const bf16* __restrict__ Kb,
                                                      const bf16* __restrict__ Vb, bf16* __restrict__ Ob) {
    __shared__ __align__(16) bf16 Kt[128 * 64];   // swizzled, DMA-staged
    __shared__ __align__(16) bf16 Vt[64 * 136];   // V^T [d][key], pad 136
    __shared__ __align__(16) bf16 Pt[4 * 32 * 64];// per-wave P strips, XOR-swizzled

    const int tid = threadIdx.x, wave = tid >> 6, lane = tid & 63;
    const int quad = lane >> 4, l15 = lane & 15;
    const int bx = blockIdx.x;
    const int ii = bx >> 5, bh = bx & 31;
    const int qtile = (ii < 8) ? (15 - ii) : (ii - 8);
    const size_t hoff = (size_t)bh * SS * HD;
    const bf16* Qg = Qb + hoff + (size_t)qtile * 128 * HD;

    // Q B-frags, register-resident (already scaled by 0.125*log2e)
    bf16x8_t qf[2][2];
#pragma unroll
    for (int qt = 0; qt < 2; qt++)
#pragma unroll
        for (int ks = 0; ks < 2; ks++)
            qf[qt][ks] = *(const bf16x8_t*)(Qg + (wave * 32 + qt * 16 + l15) * HD + ks * 32 + quad * 8);

    f32x4 o[2][4];
#pragma unroll
    for (int qt = 0; qt < 2; qt++)
#pragma unroll
        for (int nO = 0; nO < 4; nO++) {
            o[qt][nO][0] = 0.f; o[qt][nO][1] = 0.f; o[qt][nO][2] = 0.f; o[qt][nO][3] = 0.f;
        }
    float mrow[2] = {-__builtin_inff(), -__builtin_inff()};
    float lrow[2] = {0.f, 0.f};

    bf16* Pw = &Pt[wave * 2048];

    for (int j = 0; j <= qtile; j++) {
        __syncthreads();
        // K tile DMA, swizzled: row chunk c' holds global chunk c'^(row&7)
        const bf16* Kg = Kb + hoff + (size_t)j * 128 * HD;
#pragma unroll
        for (int t = 0; t < 4; t++) {
            int n = t * 256 + tid;
            int row = n >> 3, gc = (n & 7) ^ (row & 7);
            gl_lds16(Kg + row * HD + gc * 8, &Kt[(t * 256 + wave * 64) * 8]);
        }
        // V transpose staging: 4 x b128 loads -> 8 x b64 writes per thread
        const bf16* Vg = Vb + hoff + (size_t)j * 128 * HD;
        {
            int k0 = (tid & 31) * 4, d0 = (tid >> 5) * 8;
            bf16x8_t v0 = *(const bf16x8_t*)(Vg + (k0 + 0) * HD + d0);
            bf16x8_t v1 = *(const bf16x8_t*)(Vg + (k0 + 1) * HD + d0);
            bf16x8_t v2 = *(const bf16x8_t*)(Vg + (k0 + 2) * HD + d0);
            bf16x8_t v3 = *(const bf16x8_t*)(Vg + (k0 + 3) * HD + d0);
#pragma unroll
            for (int jj = 0; jj < 8; jj++) {
                bf16x4_t w;
                w.x = v0[jj]; w.y = v1[jj]; w.z = v2[jj]; w.w = v3[jj];
                *(bf16x4_t*)&Vt[(d0 + jj) * 136 + k0] = w;
            }
        }
        __syncthreads();

        const bool diag = (j == qtile);
#pragma unroll 1
        for (int kh = 0; kh < 2; kh++) {
            if (diag && kh == 1 && wave < 2) break;  // rows 0..63 fully masked vs keys 64..127

            // S^T = K * Q^T : st[kt][qt], key = kh*64 + kt*16 + quad*4 + r, qrow = qt*16 + l15
            f32x4 st[4][2];
#pragma unroll
            for (int kt = 0; kt < 4; kt++)
#pragma unroll
                for (int qt = 0; qt < 2; qt++) {
                    st[kt][qt][0] = 0.f; st[kt][qt][1] = 0.f; st[kt][qt][2] = 0.f; st[kt][qt][3] = 0.f;
                }
#pragma unroll
            for (int ks = 0; ks < 2; ks++) {
#pragma unroll
                for (int kt = 0; kt < 4; kt++) {
                    int R = (kh * 4 + kt) * 16 + l15;
                    bf16x8_t kf = *(const bf16x8_t*)&Kt[R * HD + ((((ks << 2) | quad) ^ (R & 7)) << 3)];
#pragma unroll
                    for (int qt = 0; qt < 2; qt++)
                        st[kt][qt] = __builtin_amdgcn_mfma_f32_16x16x32_bf16(kf, qf[qt][ks], st[kt][qt], 0, 0, 0);
                }
            }
            if (diag) {
#pragma unroll
                for (int kt = 0; kt < 4; kt++)
#pragma unroll
                    for (int qt = 0; qt < 2; qt++)
#pragma unroll
                        for (int r = 0; r < 4; r++) {
                            int key = kh * 64 + kt * 16 + quad * 4 + r;
                            int row = wave * 32 + qt * 16 + l15;
                            if (key > row) st[kt][qt][r] = -__builtin_inff();
                        }
            }

            // online softmax (values already in log2 units)
#pragma unroll
            for (int qt = 0; qt < 2; qt++) {
                float mx = -__builtin_inff();
#pragma unroll
                for (int kt = 0; kt < 4; kt++)
#pragma unroll
                    for (int r = 0; r < 4; r++) mx = fmaxf(mx, st[kt][qt][r]);
                mx = fmaxf(mx, __shfl_xor(mx, 16));
                mx = fmaxf(mx, __shfl_xor(mx, 32));
                float mnew = fmaxf(mrow[qt], mx);
                float alpha = exp2f(mrow[qt] - mnew);
                mrow[qt] = mnew;
                float sum = 0.f;
                const int row = qt * 16 + l15;
#pragma unroll
                for (int kt = 0; kt < 4; kt++) {
                    float p0 = exp2f(st[kt][qt][0] - mnew);
                    float p1 = exp2f(st[kt][qt][1] - mnew);
                    float p2 = exp2f(st[kt][qt][2] - mnew);
                    float p3 = exp2f(st[kt][qt][3] - mnew);
                    sum += (p0 + p1) + (p2 + p3);
                    bf16x4_t pb;
                    pb.x = (bf16)p0; pb.y = (bf16)p1; pb.z = (bf16)p2; pb.w = (bf16)p3;
                    int c = kt * 2 + (quad >> 1);
                    *(bf16x4_t*)&Pw[row * 64 + ((c ^ (row & 7)) << 3) + ((quad & 1) << 2)] = pb;
                }
                sum += __shfl_xor(sum, 16);
                sum += __shfl_xor(sum, 32);
                lrow[qt] = lrow[qt] * alpha + sum;
                // broadcast alpha (indexed by l15=row) to O rows (quad*4+r)
#pragma unroll
                for (int r = 0; r < 4; r++) {
                    float a = __shfl(alpha, (lane & 48) | (quad * 4 + r));
#pragma unroll
                    for (int nO = 0; nO < 4; nO++) o[qt][nO][r] *= a;
                }
            }

            // O += P * V^T-frags
#pragma unroll
            for (int ks = 0; ks < 2; ks++) {
                bf16x8_t pf[2];
#pragma unroll
                for (int qt = 0; qt < 2; qt++) {
                    int row = qt * 16 + l15;
                    int c = (ks << 2) | quad;
                    pf[qt] = *(const bf16x8_t*)&Pw[row * 64 + ((c ^ (row & 7)) << 3)];
                }
#pragma unroll
                for (int nO = 0; nO < 4; nO++) {
                    bf16x8_t vf = *(const bf16x8_t*)&Vt[(nO * 16 + l15) * 136 + kh * 64 + ks * 32 + quad * 8];
#pragma unroll
                    for (int qt = 0; qt < 2; qt++)
                        o[qt][nO] = __builtin_amdgcn_mfma_f32_16x16x32_bf16(pf[qt], vf, o[qt][nO], 0, 0, 0);
                }
            }
        }
    }

    // epilogue: normalize rows and write Ob [B, S, H*64]
    const int bb = bh >> 4, hh = bh & 15;
#pragma unroll
    for (int qt = 0; qt < 2; qt++) {
#pragma unroll
        for (int r = 0; r < 4; r++) {
            float linv = 1.f / __shfl(lrow[qt], (lane & 48) | (quad * 4 + r));
            int srow = qtile * 128 + wave * 32 + qt * 16 + quad * 4 + r;
#pragma unroll
            for (int nO = 0; nO < 4; nO++)
                Ob[((size_t)(bb * SS + srow)) * DD + hh * HD + nO * 16 + l15] = (bf16)(o[qt][nO][r] * linv);
        }
    }
}

// ---------------- host launcher ----------------
extern "C" void kernel_launch(void* const* d_in, const int* in_sizes, int n_in,
                              void* d_out, int out_size, void* d_ws, size_t ws_size,
                              hipStream_t stream) {
    (void)in_sizes; (void)n_in; (void)out_size; (void)ws_size;
    const float* h  = (const float*)d_in[0];
    const float* Wq = (const float*)d_in[1];
    const float* bq = (const float*)d_in[2];
    const float* Wk = (const float*)d_in[3];
    const float* bk = (const float*)d_in[4];
    const float* Wv = (const float*)d_in[5];
    const float* bv = (const float*)d_in[6];
    const float* Wo = (const float*)d_in[7];
    const float* bo = (const float*)d_in[8];
    float* out = (float*)d_out;

    char* ws = (char*)d_ws;
    bf16* hbf  = (bf16*)(ws);                                  // 8,388,608  h bf16
    bf16* wqkv = (bf16*)(ws + 8388608);                        // 6,291,456  Wq|Wk|Wv
    bf16* wo   = (bf16*)(ws + 8388608 + 6291456);              // 2,097,152  Wo
    bf16* Qb   = (bf16*)(ws + 16777216);                       // 8,388,608  [B,H,S,64] (scaled)
    bf16* Kb   = (bf16*)(ws + 16777216 + 8388608);
    bf16* Vb   = (bf16*)(ws + 16777216 + 2 * 8388608);
    bf16* Ob   = (bf16*)(ws + 16777216 + 3 * 8388608);         // [B,S,H*64]

    cast_all<<<8192, 256, 0, stream>>>(h, Wq, Wk, Wv, Wo, hbf);
    gemm_qkv<<<dim3(32, 24), 256, 0, stream>>>(hbf, wqkv, bq, bk, bv, Qb, Kb, Vb);
    attn_kernel<<<512, 256, 0, stream>>>(Qb, Kb, Vb, Ob);
    gemm_out<<<dim3(32, 8), 256, 0, stream>>>(Ob, wo, bo, out);
}

// Round 4
// 191.840 us; speedup vs baseline: 1.3378x; 1.0722x over previous
//
#include <hip/hip_runtime.h>
#include <stdint.h>

typedef __bf16 bf16;
typedef __bf16 bf16x4_t __attribute__((ext_vector_type(4)));
typedef __bf16 bf16x8_t __attribute__((ext_vector_type(8)));
typedef float f32x4 __attribute__((ext_vector_type(4)));

static constexpr int NB = 2, SS = 2048, DD = 1024, NH = 16, HD = 64;

__device__ __forceinline__ void gl_lds16(const void* g, void* l) {
    __builtin_amdgcn_global_load_lds((__attribute__((address_space(1))) void*)g,
                                     (__attribute__((address_space(3))) void*)l, 16, 0, 0);
}

// ---------------- fused fp32 -> bf16 cast of h + Wq + Wk + Wv + Wo ----------------
__global__ __launch_bounds__(256) void cast_all(const float* __restrict__ h,
                                                const float* __restrict__ Wq,
                                                const float* __restrict__ Wk,
                                                const float* __restrict__ Wv,
                                                const float* __restrict__ Wo,
                                                bf16* __restrict__ dst) {
    int i = blockIdx.x * 256 + threadIdx.x;  // float4 index, grid covers exactly 2097152
    const float* src;
    int off;
    if (i < 1048576) { src = h; off = i; }
    else {
        int r = i - 1048576;
        int w = r >> 18;
        off = r & 262143;
        src = (w == 0) ? Wq : (w == 1) ? Wk : (w == 2) ? Wv : Wo;
    }
    float4 v = reinterpret_cast<const float4*>(src)[off];
    bf16x4_t o;
    o.x = (bf16)v.x; o.y = (bf16)v.y; o.z = (bf16)v.z; o.w = (bf16)v.w;
    reinterpret_cast<bf16x4_t*>(dst)[i] = o;
}

// ---------------- 128x128 NT-GEMM mainloop (m97 structure) ----------------
__device__ __forceinline__ void gemm128_mainloop(const bf16* __restrict__ Ablk,
                                                 const bf16* __restrict__ Bblk,
                                                 int K, f32x4 acc[4][4]) {
    __shared__ __align__(16) bf16 As[128 * 32];
    __shared__ __align__(16) bf16 Bs[128 * 32];
    const int tid = threadIdx.x;
    const int wave = tid >> 6, lane = tid & 63;
    const int quad = lane >> 4, l15 = lane & 15;
    const int wm = wave >> 1, wn = wave & 1;

#pragma unroll
    for (int mi = 0; mi < 4; mi++)
#pragma unroll
        for (int ni = 0; ni < 4; ni++) {
            acc[mi][ni][0] = 0.f; acc[mi][ni][1] = 0.f;
            acc[mi][ni][2] = 0.f; acc[mi][ni][3] = 0.f;
        }

    const int n0c = tid;
    const int r0 = n0c >> 2, c0 = (n0c & 3) ^ ((r0 >> 1) & 3);
    const int n1c = 256 + tid;
    const int r1 = n1c >> 2, c1 = (n1c & 3) ^ ((r1 >> 1) & 3);

    for (int kk = 0; kk < K; kk += 32) {
        __syncthreads();
        gl_lds16(Ablk + (size_t)r0 * K + kk + c0 * 8, &As[(wave * 64) * 8]);
        gl_lds16(Ablk + (size_t)r1 * K + kk + c1 * 8, &As[(256 + wave * 64) * 8]);
        gl_lds16(Bblk + (size_t)r0 * K + kk + c0 * 8, &Bs[(wave * 64) * 8]);
        gl_lds16(Bblk + (size_t)r1 * K + kk + c1 * 8, &Bs[(256 + wave * 64) * 8]);
        __syncthreads();

        bf16x8_t a[4], b[4];
#pragma unroll
        for (int mi = 0; mi < 4; mi++) {
            int R = wm * 64 + mi * 16 + l15;
            a[mi] = *(const bf16x8_t*)&As[R * 32 + ((quad ^ ((R >> 1) & 3)) << 3)];
        }
#pragma unroll
        for (int ni = 0; ni < 4; ni++) {
            int R = wn * 64 + ni * 16 + l15;
            b[ni] = *(const bf16x8_t*)&Bs[R * 32 + ((quad ^ ((R >> 1) & 3)) << 3)];
        }
#pragma unroll
        for (int mi = 0; mi < 4; mi++)
#pragma unroll
            for (int ni = 0; ni < 4; ni++)
                acc[mi][ni] = __builtin_amdgcn_mfma_f32_16x16x32_bf16(a[mi], b[ni], acc[mi][ni], 0, 0, 0);
    }
}

// ---------------- 64x128 NT-GEMM mainloop (more blocks for small GEMMs) ----------------
__device__ __forceinline__ void gemm64_mainloop(const bf16* __restrict__ Ablk,
                                                const bf16* __restrict__ Bblk,
                                                int K, f32x4 acc[2][4]) {
    __shared__ __align__(16) bf16 As[64 * 32];
    __shared__ __align__(16) bf16 Bs[128 * 32];
    const int tid = threadIdx.x;
    const int wave = tid >> 6, lane = tid & 63;
    const int quad = lane >> 4, l15 = lane & 15;
    const int wm = wave >> 1, wn = wave & 1;

#pragma unroll
    for (int mi = 0; mi < 2; mi++)
#pragma unroll
        for (int ni = 0; ni < 4; ni++) {
            acc[mi][ni][0] = 0.f; acc[mi][ni][1] = 0.f;
            acc[mi][ni][2] = 0.f; acc[mi][ni][3] = 0.f;
        }

    const int ra = tid >> 2, ca = (tid & 3) ^ ((ra >> 1) & 3);          // A: 256 chunks, 1 issue
    const int r0 = tid >> 2, c0 = (tid & 3) ^ ((r0 >> 1) & 3);          // B issue 0
    const int n1c = 256 + tid;
    const int r1 = n1c >> 2, c1 = (n1c & 3) ^ ((r1 >> 1) & 3);          // B issue 1

    for (int kk = 0; kk < K; kk += 32) {
        __syncthreads();
        gl_lds16(Ablk + (size_t)ra * K + kk + ca * 8, &As[(wave * 64) * 8]);
        gl_lds16(Bblk + (size_t)r0 * K + kk + c0 * 8, &Bs[(wave * 64) * 8]);
        gl_lds16(Bblk + (size_t)r1 * K + kk + c1 * 8, &Bs[(256 + wave * 64) * 8]);
        __syncthreads();

        bf16x8_t a[2], b[4];
#pragma unroll
        for (int mi = 0; mi < 2; mi++) {
            int R = wm * 32 + mi * 16 + l15;
            a[mi] = *(const bf16x8_t*)&As[R * 32 + ((quad ^ ((R >> 1) & 3)) << 3)];
        }
#pragma unroll
        for (int ni = 0; ni < 4; ni++) {
            int R = wn * 64 + ni * 16 + l15;
            b[ni] = *(const bf16x8_t*)&Bs[R * 32 + ((quad ^ ((R >> 1) & 3)) << 3)];
        }
#pragma unroll
        for (int mi = 0; mi < 2; mi++)
#pragma unroll
            for (int ni = 0; ni < 4; ni++)
                acc[mi][ni] = __builtin_amdgcn_mfma_f32_16x16x32_bf16(a[mi], b[ni], acc[mi][ni], 0, 0, 0);
    }
}

// ---------------- QKV projection ----------------
// Q is pre-scaled by 0.125 * log2(e) so attention can use exp2 directly.
__global__ __launch_bounds__(256) void gemm_qkv(const bf16* __restrict__ A, const bf16* __restrict__ Wqkv,
                                                const float* __restrict__ bq, const float* __restrict__ bk,
                                                const float* __restrict__ bv,
                                                bf16* __restrict__ Qb, bf16* __restrict__ Kb, bf16* __restrict__ Vb) {
    const int m0 = blockIdx.x * 128;
    const int n0 = blockIdx.y * 128;
    f32x4 acc[4][4];
    gemm128_mainloop(A + (size_t)m0 * DD, Wqkv + (size_t)n0 * DD, DD, acc);

    const int tid = threadIdx.x, wave = tid >> 6, lane = tid & 63;
    const int quad = lane >> 4, l15 = lane & 15;
    const int wm = wave >> 1, wn = wave & 1;

    const int which = n0 >> 10;
    const float* bias = (which == 0) ? bq : (which == 1) ? bk : bv;
    bf16* dst = (which == 0) ? Qb : (which == 1) ? Kb : Vb;
    const float sc = (which == 0) ? 0.18033688f : 1.0f;  // 0.125 * log2(e)

    const int cbase = (n0 & 1023) + wn * 64;
    const int head = cbase >> 6;
    const int bb = m0 >> 11;
    const int s0 = (m0 & 2047) + wm * 64;
    bf16* dbase = dst + ((size_t)(bb * NH + head)) * SS * HD;

#pragma unroll
    for (int ni = 0; ni < 4; ni++) {
        float bsv = bias[cbase + ni * 16 + l15];
        int hd = ni * 16 + l15;
#pragma unroll
        for (int mi = 0; mi < 4; mi++) {
#pragma unroll
            for (int r = 0; r < 4; r++) {
                int s = s0 + mi * 16 + quad * 4 + r;
                dbase[(size_t)s * HD + hd] = (bf16)((acc[mi][ni][r] + bsv) * sc);
            }
        }
    }
}

// ---------------- output projection: fp32 out, 64x128 tiles (512 blocks, 2/CU) ----------------
__global__ __launch_bounds__(256) void gemm_out(const bf16* __restrict__ A, const bf16* __restrict__ Wo,
                                                const float* __restrict__ bo, float* __restrict__ out) {
    const int m0 = blockIdx.x * 64, n0 = blockIdx.y * 128;
    f32x4 acc[2][4];
    gemm64_mainloop(A + (size_t)m0 * DD, Wo + (size_t)n0 * DD, DD, acc);

    const int tid = threadIdx.x, wave = tid >> 6, lane = tid & 63;
    const int quad = lane >> 4, l15 = lane & 15;
    const int wm = wave >> 1, wn = wave & 1;
    float* obase = out + (size_t)(m0 + wm * 32) * DD + n0 + wn * 64;
#pragma unroll
    for (int ni = 0; ni < 4; ni++) {
        float bias = bo[n0 + wn * 64 + ni * 16 + l15];
#pragma unroll
        for (int mi = 0; mi < 2; mi++)
#pragma unroll
            for (int r = 0; r < 4; r++)
                obase[(size_t)(mi * 16 + quad * 4 + r) * DD + ni * 16 + l15] = acc[mi][ni][r] + bias;
    }
}

// ---------------- causal flash attention, S^T formulation + split-KV ----------------
// 24 parts per bh (qtiles 0..7 whole, 8..15 split into two KV halves), sorted
// longest-first; 768 blocks -> 3 blocks/CU resident. Split parts write
// unnormalized O (bf16) + per-row m,l (f32, log2 domain) to workspace;
// merge_kernel combines. Unsplit parts write Ob directly.
__global__ __launch_bounds__(256, 3) void attn_kernel(const bf16* __restrict__ Qb, const bf16* __restrict__ Kb,
                                                      const bf16* __restrict__ Vb, bf16* __restrict__ Ob,
                                                      bf16* __restrict__ Opart, float* __restrict__ Ml) {
    constexpr int PQ[24]  = {15,15,14, 7,14,13,13,12, 6,12,11,11,10, 5,10, 9, 9, 8, 4, 8, 3, 2, 1, 0};
    constexpr int PJ0[24] = { 0, 8, 0, 0, 8, 0, 7, 0, 0, 7, 0, 6, 0, 0, 6, 0, 5, 0, 0, 5, 0, 0, 0, 0};
    constexpr int PJ1[24] = { 8,16, 8, 8,15, 7,14, 7, 7,13, 6,12, 6, 6,11, 5,10, 5, 5, 9, 4, 3, 2, 1};

    __shared__ __align__(16) bf16 Kt[128 * 64];   // swizzled, DMA-staged
    __shared__ __align__(16) bf16 Vt[64 * 136];   // V^T [d][key], pad 136
    __shared__ __align__(16) bf16 Pt[4 * 32 * 64];// per-wave P strips, XOR-swizzled

    const int tid = threadIdx.x, wave = tid >> 6, lane = tid & 63;
    const int quad = lane >> 4, l15 = lane & 15;
    const int bx = blockIdx.x;
    const int p = bx >> 5, bh = bx & 31;
    const int qtile = PQ[p], jbeg = PJ0[p], jend = PJ1[p];
    const bool diagpart = (jend == qtile + 1);
    const size_t hoff = (size_t)bh * SS * HD;
    const bf16* Qg = Qb + hoff + (size_t)qtile * 128 * HD;

    // Q B-frags, register-resident (already scaled by 0.125*log2e)
    bf16x8_t qf[2][2];
#pragma unroll
    for (int qt = 0; qt < 2; qt++)
#pragma unroll
        for (int ks = 0; ks < 2; ks++)
            qf[qt][ks] = *(const bf16x8_t*)(Qg + (wave * 32 + qt * 16 + l15) * HD + ks * 32 + quad * 8);

    f32x4 o[2][4];
#pragma unroll
    for (int qt = 0; qt < 2; qt++)
#pragma unroll
        for (int nO = 0; nO < 4; nO++) {
            o[qt][nO][0] = 0.f; o[qt][nO][1] = 0.f; o[qt][nO][2] = 0.f; o[qt][nO][3] = 0.f;
        }
    float mrow[2] = {-__builtin_inff(), -__builtin_inff()};
    float lrow[2] = {0.f, 0.f};

    bf16* Pw = &Pt[wave * 2048];

    for (int j = jbeg; j < jend; j++) {
        __syncthreads();
        // K tile DMA, swizzled: row chunk c' holds global chunk c'^(row&7)
        const bf16* Kg = Kb + hoff + (size_t)j * 128 * HD;
#pragma unroll
        for (int t = 0; t < 4; t++) {
            int n = t * 256 + tid;
            int row = n >> 3, gc = (n & 7) ^ (row & 7);
            gl_lds16(Kg + row * HD + gc * 8, &Kt[(t * 256 + wave * 64) * 8]);
        }
        // V transpose staging: 4 x b128 loads -> 8 x b64 writes per thread
        const bf16* Vg = Vb + hoff + (size_t)j * 128 * HD;
        {
            int k0 = (tid & 31) * 4, d0 = (tid >> 5) * 8;
            bf16x8_t v0 = *(const bf16x8_t*)(Vg + (k0 + 0) * HD + d0);
            bf16x8_t v1 = *(const bf16x8_t*)(Vg + (k0 + 1) * HD + d0);
            bf16x8_t v2 = *(const bf16x8_t*)(Vg + (k0 + 2) * HD + d0);
            bf16x8_t v3 = *(const bf16x8_t*)(Vg + (k0 + 3) * HD + d0);
#pragma unroll
            for (int jj = 0; jj < 8; jj++) {
                bf16x4_t w;
                w.x = v0[jj]; w.y = v1[jj]; w.z = v2[jj]; w.w = v3[jj];
                *(bf16x4_t*)&Vt[(d0 + jj) * 136 + k0] = w;
            }
        }
        __syncthreads();

        const bool diag = diagpart && (j == jend - 1);
#pragma unroll 1
        for (int kh = 0; kh < 2; kh++) {
            if (diag && kh == 1 && wave < 2) break;  // rows 0..63 fully masked vs keys 64..127

            // S^T = K * Q^T : st[kt][qt], key = kh*64 + kt*16 + quad*4 + r, qrow = qt*16 + l15
            f32x4 st[4][2];
#pragma unroll
            for (int kt = 0; kt < 4; kt++)
#pragma unroll
                for (int qt = 0; qt < 2; qt++) {
                    st[kt][qt][0] = 0.f; st[kt][qt][1] = 0.f; st[kt][qt][2] = 0.f; st[kt][qt][3] = 0.f;
                }
#pragma unroll
            for (int ks = 0; ks < 2; ks++) {
#pragma unroll
                for (int kt = 0; kt < 4; kt++) {
                    int R = (kh * 4 + kt) * 16 + l15;
                    bf16x8_t kf = *(const bf16x8_t*)&Kt[R * HD + ((((ks << 2) | quad) ^ (R & 7)) << 3)];
#pragma unroll
                    for (int qt = 0; qt < 2; qt++)
                        st[kt][qt] = __builtin_amdgcn_mfma_f32_16x16x32_bf16(kf, qf[qt][ks], st[kt][qt], 0, 0, 0);
                }
            }
            if (diag) {
#pragma unroll
                for (int kt = 0; kt < 4; kt++)
#pragma unroll
                    for (int qt = 0; qt < 2; qt++)
#pragma unroll
                        for (int r = 0; r < 4; r++) {
                            int key = kh * 64 + kt * 16 + quad * 4 + r;
                            int row = wave * 32 + qt * 16 + l15;
                            if (key > row) st[kt][qt][r] = -__builtin_inff();
                        }
            }

            // online softmax (values already in log2 units)
#pragma unroll
            for (int qt = 0; qt < 2; qt++) {
                float mx = -__builtin_inff();
#pragma unroll
                for (int kt = 0; kt < 4; kt++)
#pragma unroll
                    for (int r = 0; r < 4; r++) mx = fmaxf(mx, st[kt][qt][r]);
                mx = fmaxf(mx, __shfl_xor(mx, 16));
                mx = fmaxf(mx, __shfl_xor(mx, 32));
                float mnew = fmaxf(mrow[qt], mx);
                float alpha = exp2f(mrow[qt] - mnew);
                mrow[qt] = mnew;
                float sum = 0.f;
                const int row = qt * 16 + l15;
#pragma unroll
                for (int kt = 0; kt < 4; kt++) {
                    float p0 = exp2f(st[kt][qt][0] - mnew);
                    float p1 = exp2f(st[kt][qt][1] - mnew);
                    float p2 = exp2f(st[kt][qt][2] - mnew);
                    float p3 = exp2f(st[kt][qt][3] - mnew);
                    sum += (p0 + p1) + (p2 + p3);
                    bf16x4_t pb;
                    pb.x = (bf16)p0; pb.y = (bf16)p1; pb.z = (bf16)p2; pb.w = (bf16)p3;
                    int c = kt * 2 + (quad >> 1);
                    *(bf16x4_t*)&Pw[row * 64 + ((c ^ (row & 7)) << 3) + ((quad & 1) << 2)] = pb;
                }
                sum += __shfl_xor(sum, 16);
                sum += __shfl_xor(sum, 32);
                lrow[qt] = lrow[qt] * alpha + sum;
                // broadcast alpha (indexed by l15=row) to O rows (quad*4+r)
#pragma unroll
                for (int r = 0; r < 4; r++) {
                    float a = __shfl(alpha, (lane & 48) | (quad * 4 + r));
#pragma unroll
                    for (int nO = 0; nO < 4; nO++) o[qt][nO][r] *= a;
                }
            }

            // O += P * V^T-frags
#pragma unroll
            for (int ks = 0; ks < 2; ks++) {
                bf16x8_t pf[2];
#pragma unroll
                for (int qt = 0; qt < 2; qt++) {
                    int row = qt * 16 + l15;
                    int c = (ks << 2) | quad;
                    pf[qt] = *(const bf16x8_t*)&Pw[row * 64 + ((c ^ (row & 7)) << 3)];
                }
#pragma unroll
                for (int nO = 0; nO < 4; nO++) {
                    bf16x8_t vf = *(const bf16x8_t*)&Vt[(nO * 16 + l15) * 136 + kh * 64 + ks * 32 + quad * 8];
#pragma unroll
                    for (int qt = 0; qt < 2; qt++)
                        o[qt][nO] = __builtin_amdgcn_mfma_f32_16x16x32_bf16(pf[qt], vf, o[qt][nO], 0, 0, 0);
                }
            }
        }
    }

    if (qtile >= 8) {
        // split part: write unnormalized O (bf16) + m,l (f32)
        const int pidx = ((bh << 3) + (qtile - 8)) * 2 + (jbeg != 0 ? 1 : 0);
        bf16* Op = Opart + (size_t)pidx * (128 * 64);
        float* mlp = Ml + (size_t)pidx * 256;
#pragma unroll
        for (int qt = 0; qt < 2; qt++) {
            if (quad == 0) {
                mlp[wave * 32 + qt * 16 + l15] = mrow[qt];
                mlp[128 + wave * 32 + qt * 16 + l15] = lrow[qt];
            }
#pragma unroll
            for (int r = 0; r < 4; r++) {
                int row = wave * 32 + qt * 16 + quad * 4 + r;
#pragma unroll
                for (int nO = 0; nO < 4; nO++)
                    Op[row * 64 + nO * 16 + l15] = (bf16)o[qt][nO][r];
            }
        }
    } else {
        // whole tile: normalize and write Ob [B, S, H*64]
        const int bb = bh >> 4, hh = bh & 15;
#pragma unroll
        for (int qt = 0; qt < 2; qt++) {
#pragma unroll
            for (int r = 0; r < 4; r++) {
                float linv = 1.f / __shfl(lrow[qt], (lane & 48) | (quad * 4 + r));
                int srow = qtile * 128 + wave * 32 + qt * 16 + quad * 4 + r;
#pragma unroll
                for (int nO = 0; nO < 4; nO++)
                    Ob[((size_t)(bb * SS + srow)) * DD + hh * HD + nO * 16 + l15] = (bf16)(o[qt][nO][r] * linv);
            }
        }
    }
}

// ---------------- merge two KV-half partials -> Ob (qtiles 8..15) ----------------
__global__ __launch_bounds__(256) void merge_kernel(const bf16* __restrict__ Opart,
                                                    const float* __restrict__ Ml,
                                                    bf16* __restrict__ Ob) {
    const int bh = blockIdx.x >> 3, q8 = blockIdx.x & 7;  // qtile = 8 + q8
    const int p0 = ((bh << 3) + q8) * 2, p1 = p0 + 1;
    const int t = threadIdx.x, row = t >> 1, c0 = (t & 1) * 32;
    float m0 = Ml[p0 * 256 + row], l0 = Ml[p0 * 256 + 128 + row];
    float m1 = Ml[p1 * 256 + row], l1 = Ml[p1 * 256 + 128 + row];
    float M = fmaxf(m0, m1);
    float w0 = exp2f(m0 - M), w1 = exp2f(m1 - M);
    float inv = 1.f / (l0 * w0 + l1 * w1);
    w0 *= inv; w1 *= inv;
    const bf16* O0 = Opart + (size_t)p0 * (128 * 64) + row * 64 + c0;
    const bf16* O1 = Opart + (size_t)p1 * (128 * 64) + row * 64 + c0;
    const int bb = bh >> 4, hh = bh & 15;
    const int srow = (8 + q8) * 128 + row;
    bf16* dst = Ob + ((size_t)(bb * SS + srow)) * DD + hh * HD + c0;
#pragma unroll
    for (int i = 0; i < 4; i++) {
        bf16x8_t a = *(const bf16x8_t*)(O0 + i * 8);
        bf16x8_t b = *(const bf16x8_t*)(O1 + i * 8);
        bf16x8_t r;
#pragma unroll
        for (int jj = 0; jj < 8; jj++)
            r[jj] = (bf16)((float)a[jj] * w0 + (float)b[jj] * w1);
        *(bf16x8_t*)(dst + i * 8) = r;
    }
}

// ---------------- host launcher ----------------
extern "C" void kernel_launch(void* const* d_in, const int* in_sizes, int n_in,
                              void* d_out, int out_size, void* d_ws, size_t ws_size,
                              hipStream_t stream) {
    (void)in_sizes; (void)n_in; (void)out_size; (void)ws_size;
    const float* h  = (const float*)d_in[0];
    const float* Wq = (const float*)d_in[1];
    const float* bq = (const float*)d_in[2];
    const float* Wk = (const float*)d_in[3];
    const float* bk = (const float*)d_in[4];
    const float* Wv = (const float*)d_in[5];
    const float* bv = (const float*)d_in[6];
    const float* Wo = (const float*)d_in[7];
    const float* bo = (const float*)d_in[8];
    float* out = (float*)d_out;

    char* ws = (char*)d_ws;
    bf16* hbf  = (bf16*)(ws);                                  // 8,388,608  h bf16 (dead after gemm_qkv)
    bf16* wqkv = (bf16*)(ws + 8388608);                        // 6,291,456  Wq|Wk|Wv (dead after gemm_qkv)
    bf16* wo   = (bf16*)(ws + 8388608 + 6291456);              // 2,097,152  Wo
    bf16* Qb   = (bf16*)(ws + 16777216);                       // 8,388,608  [B,H,S,64] (scaled)
    bf16* Kb   = (bf16*)(ws + 16777216 + 8388608);
    bf16* Vb   = (bf16*)(ws + 16777216 + 2 * 8388608);
    bf16* Ob   = (bf16*)(ws + 16777216 + 3 * 8388608);         // [B,S,H*64]
    // attention split partials reuse the dead cast region:
    bf16*  Opart = (bf16*)(ws);                                // 512 x 128x64 bf16 = 8,388,608
    float* Ml    = (float*)(ws + 8388608);                     // 512 x 256 f32   =   524,288

    cast_all<<<8192, 256, 0, stream>>>(h, Wq, Wk, Wv, Wo, hbf);
    gemm_qkv<<<dim3(32, 24), 256, 0, stream>>>(hbf, wqkv, bq, bk, bv, Qb, Kb, Vb);
    attn_kernel<<<768, 256, 0, stream>>>(Qb, Kb, Vb, Ob, Opart, Ml);
    merge_kernel<<<256, 256, 0, stream>>>(Opart, Ml, Ob);
    gemm_out<<<dim3(64, 8), 256, 0, stream>>>(Ob, wo, bo, out);
}